// Round 1
// baseline (878.511 us; speedup 1.0000x reference)
//
#include <hip/hip_runtime.h>
#include <math.h>

#define NP   132
#define NPP  (NP*NP)          // 17424
#define NCH  64
#define NBAT 4
#define NIMG (NBAT*NCH)       // 256
#define NX   128
#define NO   256
#define TWO_PI 6.2831853071795864769f

// ws layout (floats):
//   H   : [NCH ][NPP][2]   per-channel spectral transfer function
//   G1/P: [NIMG][NPP][2]   stage1 output; reused for stage3 output
//   Ft  : [NIMG][NPP][2]   stage2 output (spectrum * H)
//   rho : [NIMG][NPP]      real correction image
static const size_t OFF_H   = 0;
static const size_t OFF_G1  = OFF_H  + (size_t)NCH*NPP*2;
static const size_t OFF_FT  = OFF_G1 + (size_t)NIMG*NPP*2;
static const size_t OFF_RHO = OFF_FT + (size_t)NIMG*NPP*2;
// total = 24,532,992 floats = ~93.6 MiB of d_ws

__global__ __launch_bounds__(256) void k_compute_H(
    const float* __restrict__ wgt, const float* __restrict__ bias,
    float2* __restrict__ H) {
  int idx = blockIdx.x * 256 + threadIdx.x;
  int c = blockIdx.y;
  if (idx >= NPP) return;
  int u = idx / NP, v = idx - (idx / NP) * NP;
  float k[3][3];
#pragma unroll
  for (int i = 0; i < 3; i++)
#pragma unroll
    for (int j = 0; j < 3; j++) k[i][j] = wgt[c*9 + i*3 + j];
  // even-subsampled autocorrelation a2[p0][p1], p in {-1,0,1}^2
  float invW = 0.f;
#pragma unroll
  for (int p0 = -1; p0 <= 1; p0++)
#pragma unroll
    for (int p1 = -1; p1 <= 1; p1++) {
      float s = 0.f;
#pragma unroll
      for (int i = 0; i < 3; i++)
#pragma unroll
        for (int j = 0; j < 3; j++) {
          int i2 = i - 2*p0, j2 = j - 2*p1;
          if (i2 >= 0 && i2 < 3 && j2 >= 0 && j2 < 3) s += k[i][j]*k[i2][j2];
        }
      float ang = TWO_PI * (float)(u*p0 + v*p1) / (float)NP;
      invW += s * cosf(ang);
    }
  // collapsed 2x2 kernel B-hat
  float B00 = k[0][0]+k[0][1]+k[1][0]+k[1][1];
  float B10 = k[2][0]+k[2][1];
  float B01 = k[0][2]+k[1][2];
  float B11 = k[2][2];
  float su, cu, sv, cv, suv, cuv;
  sincosf(TWO_PI*(float)u/(float)NP, &su, &cu);
  sincosf(TWO_PI*(float)v/(float)NP, &sv, &cv);
  sincosf(TWO_PI*(float)(u+v)/(float)NP, &suv, &cuv);
  float Bre = B00 + B10*cu + B01*cv + B11*cuv;
  float Bim = -(B10*su + B01*sv + B11*suv);
  float alpha = 1.f/(1.f + expf(9.f - bias[c])) + 1e-5f;
  float d = invW + alpha;
  H[(size_t)c*NPP + idx] = make_float2((1.f - Bre)/d, (-Bim)/d);
}

// stage1: G1[u,n1] = sum_n0 w^(u*n0) * y[n0,n1], y = wrap-padded x (read in place)
__global__ __launch_bounds__(256) void k_stage1(
    const float* __restrict__ x, float2* __restrict__ G1) {
  __shared__ float2 tab[NP];
  int tid = threadIdx.x, img = blockIdx.y, u0 = blockIdx.x * 4;
  if (tid < NP) { float s, c; sincosf(TWO_PI*(float)tid/(float)NP, &s, &c); tab[tid] = make_float2(c, s); }
  __syncthreads();
  const float* xim = x + (size_t)img*NX*NX;
  for (int e = tid; e < 4*NP; e += 256) {
    int r = e / NP, n1 = e - r*NP, u = u0 + r;
    int xc = (n1 + 126) & 127;
    float ar = 0.f, ai = 0.f;
    int kk = 0;
    for (int n0 = 0; n0 < NP; n0++) {
      int xr = (n0 + 126) & 127;
      float yv = xim[xr*NX + xc];
      float2 t = tab[kk];
      ar += t.x * yv; ai -= t.y * yv;
      kk += u; if (kk >= NP) kk -= NP;
    }
    G1[(size_t)img*NPP + u*NP + n1] = make_float2(ar, ai);
  }
}

// stage2: Ft[u,v] = (sum_n1 G1[u,n1] * w^(n1*v)) * H[c][u,v]
__global__ __launch_bounds__(256) void k_stage2(
    const float2* __restrict__ G1, const float2* __restrict__ H,
    float2* __restrict__ Ft) {
  __shared__ float2 tab[NP];
  __shared__ float2 lg[4*NP];
  int tid = threadIdx.x, img = blockIdx.y, u0 = blockIdx.x * 4;
  int c = img & 63;
  if (tid < NP) { float s, cc; sincosf(TWO_PI*(float)tid/(float)NP, &s, &cc); tab[tid] = make_float2(cc, s); }
  for (int e = tid; e < 4*NP; e += 256) {
    int r = e / NP, col = e - r*NP;
    lg[e] = G1[(size_t)img*NPP + (u0+r)*NP + col];
  }
  __syncthreads();
  const float2* Hc = H + (size_t)c*NPP;
  for (int e = tid; e < 4*NP; e += 256) {
    int r = e / NP, v = e - r*NP, u = u0 + r;
    float ar = 0.f, ai = 0.f;
    int kk = 0;
    for (int n1 = 0; n1 < NP; n1++) {
      float2 g = tab[kk];            // w^(n1*v) = (g.x, -g.y)
      float2 gv = lg[r*NP + n1];
      ar += gv.x*g.x + gv.y*g.y;
      ai += gv.y*g.x - gv.x*g.y;
      kk += v; if (kk >= NP) kk -= NP;
    }
    float2 h = Hc[u*NP + v];
    Ft[(size_t)img*NPP + u*NP + v] = make_float2(ar*h.x - ai*h.y, ar*h.y + ai*h.x);
  }
}

// stage3: P[n0,v] = sum_u conj(w)^(n0*u) * Ft[u,v]   (written into G1 buffer)
__global__ __launch_bounds__(256) void k_stage3(
    const float2* __restrict__ Ft, float2* __restrict__ P) {
  __shared__ float2 tab[NP];
  int tid = threadIdx.x, img = blockIdx.y, n00 = blockIdx.x * 4;
  if (tid < NP) { float s, c; sincosf(TWO_PI*(float)tid/(float)NP, &s, &c); tab[tid] = make_float2(c, s); }
  __syncthreads();
  const float2* Fi = Ft + (size_t)img*NPP;
  for (int e = tid; e < 4*NP; e += 256) {
    int r = e / NP, v = e - r*NP, n0 = n00 + r;
    float ar = 0.f, ai = 0.f;
    int kk = 0;
    for (int u = 0; u < NP; u++) {
      float2 f = Fi[u*NP + v];
      float2 t = tab[kk];            // conj(w)^(n0*u) = (t.x, +t.y)
      ar += f.x*t.x - f.y*t.y;
      ai += f.x*t.y + f.y*t.x;
      kk += n0; if (kk >= NP) kk -= NP;
    }
    P[(size_t)img*NPP + n0*NP + v] = make_float2(ar, ai);
  }
}

// stage4: rho[n0,n1] = Re( sum_v P[n0,v] * conj(w)^(v*n1) ) / NPP
__global__ __launch_bounds__(256) void k_stage4(
    const float2* __restrict__ P, float* __restrict__ rho) {
  __shared__ float2 tab[NP];
  __shared__ float2 lp[4*NP];
  int tid = threadIdx.x, img = blockIdx.y, n00 = blockIdx.x * 4;
  if (tid < NP) { float s, c; sincosf(TWO_PI*(float)tid/(float)NP, &s, &c); tab[tid] = make_float2(c, s); }
  for (int e = tid; e < 4*NP; e += 256) {
    int r = e / NP, col = e - r*NP;
    lp[e] = P[(size_t)img*NPP + (n00+r)*NP + col];
  }
  __syncthreads();
  for (int e = tid; e < 4*NP; e += 256) {
    int r = e / NP, n1 = e - r*NP, n0 = n00 + r;
    float acc = 0.f;
    int kk = 0;
    for (int v = 0; v < NP; v++) {
      float2 p = lp[r*NP + v];
      float2 t = tab[kk];
      acc += p.x*t.x - p.y*t.y;
      kk += n1; if (kk >= NP) kk -= NP;
    }
    rho[(size_t)img*NPP + n0*NP + n1] = acc * (1.0f/(float)NPP);
  }
}

// epilogue: out[o] = gelu( x_up + subpixel 3x3 taps of K over zero-upsampled rho )
__global__ __launch_bounds__(256) void k_epilogue(
    const float* __restrict__ x, const float* __restrict__ wgt,
    const float* __restrict__ rho, float* __restrict__ out) {
  int idx = blockIdx.x * 256 + threadIdx.x;   // < 4*64*256*256
  int o1 = idx & 255;
  int o0 = (idx >> 8) & 255;
  int img = idx >> 16;
  int c = img & 63;
  int n0 = (o0 + 4) >> 1, n1 = (o1 + 4) >> 1;
  int p0 = o0 & 1, p1 = o1 & 1;
  const float* rim = rho + (size_t)img*NPP;
  int base = n0*NP + n1;
  float r00 = rim[base], r01 = rim[base+1], r10 = rim[base+NP], r11 = rim[base+NP+1];
  const float* w = wgt + c*9;
  float wa = p0 ? (p1 ? w[0] : w[1]) : (p1 ? w[3] : w[4]);
  float wb = p1 ? (p0 ? w[2] : w[5]) : 0.f;
  float wc = p0 ? (p1 ? w[6] : w[7]) : 0.f;
  float wd = (p0 & p1) ? w[8] : 0.f;
  float S = wa*r00 + wb*r01 + wc*r10 + wd*r11;
  float xv = x[(size_t)img*NX*NX + (n0-2)*NX + (n1-2)];
  float z = xv + S;
  out[idx] = 0.5f*z*(1.0f + erff(z*0.70710678118654752f));
}

extern "C" void kernel_launch(void* const* d_in, const int* in_sizes, int n_in,
                              void* d_out, int out_size, void* d_ws, size_t ws_size,
                              hipStream_t stream) {
  const float* x    = (const float*)d_in[0];
  const float* wgt  = (const float*)d_in[1];
  const float* bias = (const float*)d_in[2];
  float* ws = (float*)d_ws;
  float2* H   = (float2*)(ws + OFF_H);
  float2* G1  = (float2*)(ws + OFF_G1);   // also holds P after stage3
  float2* Ft  = (float2*)(ws + OFF_FT);
  float*  rho = ws + OFF_RHO;
  float* out = (float*)d_out;

  k_compute_H<<<dim3((NPP + 255)/256, NCH), 256, 0, stream>>>(wgt, bias, H);
  k_stage1  <<<dim3(33, NIMG), 256, 0, stream>>>(x, G1);
  k_stage2  <<<dim3(33, NIMG), 256, 0, stream>>>(G1, H, Ft);
  k_stage3  <<<dim3(33, NIMG), 256, 0, stream>>>(Ft, G1);
  k_stage4  <<<dim3(33, NIMG), 256, 0, stream>>>(G1, rho);
  k_epilogue<<<(NIMG*NO*NO)/256, 256, 0, stream>>>(x, wgt, rho, out);
}

// Round 2
// 462.227 us; speedup vs baseline: 1.9006x; 1.9006x over previous
//
#include <hip/hip_runtime.h>
#include <math.h>

#define NP   132
#define NV   67            // Hermitian half-spectrum (0..66), 132 even -> 66 = Nyquist
#define NPP  (NP*NP)       // 17424
#define NCH  64
#define NIMG 256
#define NX   128
#define NO   256
#define TWO_PI 6.2831853071795864769f

// ws layout (floats):
//   H   : [NCH ][NV][NP][2]   per-channel transfer fn, transposed [v][u]
//   A   : [NIMG][NP][NV][2]   row-DFT of y
//   T   : [NIMG][NV][NP][2]   H * col-DFT, transposed [v][u]
//   U   : [NIMG][NV][NP][2]   col-inverse, transposed [v][n0]
//   rho : [NIMG][NPP]         real correction image
static const size_t OFF_H   = 0;
static const size_t OFF_A   = OFF_H + (size_t)NCH*NV*NP*2;
static const size_t OFF_T   = OFF_A + (size_t)NIMG*NP*NV*2;
static const size_t OFF_U   = OFF_T + (size_t)NIMG*NV*NP*2;
static const size_t OFF_RHO = OFF_U + (size_t)NIMG*NV*NP*2;
// total ~19.2M floats ~77 MiB

__global__ __launch_bounds__(256) void k_compute_H(
    const float* __restrict__ wgt, const float* __restrict__ bias,
    float2* __restrict__ H) {
  int idx = blockIdx.x * 256 + threadIdx.x;   // over NV*NP
  int c = blockIdx.y;
  if (idx >= NV*NP) return;
  int u = idx % NP, v = idx / NP;             // u = row freq, v = col freq
  float k[3][3];
#pragma unroll
  for (int i = 0; i < 3; i++)
#pragma unroll
    for (int j = 0; j < 3; j++) k[i][j] = wgt[c*9 + i*3 + j];
  float invW = 0.f;
#pragma unroll
  for (int p0 = -1; p0 <= 1; p0++)
#pragma unroll
    for (int p1 = -1; p1 <= 1; p1++) {
      float s = 0.f;
#pragma unroll
      for (int i = 0; i < 3; i++)
#pragma unroll
        for (int j = 0; j < 3; j++) {
          int i2 = i - 2*p0, j2 = j - 2*p1;
          if (i2 >= 0 && i2 < 3 && j2 >= 0 && j2 < 3) s += k[i][j]*k[i2][j2];
        }
      float ang = TWO_PI * (float)(u*p0 + v*p1) / (float)NP;
      invW += s * cosf(ang);
    }
  float B00 = k[0][0]+k[0][1]+k[1][0]+k[1][1];
  float B10 = k[2][0]+k[2][1];
  float B01 = k[0][2]+k[1][2];
  float B11 = k[2][2];
  float su, cu, sv, cv, suv, cuv;
  sincosf(TWO_PI*(float)u/(float)NP, &su, &cu);
  sincosf(TWO_PI*(float)v/(float)NP, &sv, &cv);
  sincosf(TWO_PI*(float)(u+v)/(float)NP, &suv, &cuv);
  float Bre = B00 + B10*cu + B01*cv + B11*cuv;
  float Bim = -(B10*su + B01*sv + B11*suv);
  float alpha = 1.f/(1.f + expf(9.f - bias[c])) + 1e-5f;
  float d = invW + alpha;
  H[((size_t)c*NV + v)*NP + u] = make_float2((1.f - Bre)/d, (-Bim)/d);
}

// S1 row-DFT: A[n0][v] = sum_n1 y[n0][n1] W^(v n1), v=0..66. 4 rows/block, all LDS.
__global__ __launch_bounds__(256) void k_s1(
    const float* __restrict__ x, float2* __restrict__ A) {
  __shared__ float2 tab[NP];
  __shared__ float  ly[4*NP];
  int tid = threadIdx.x, img = blockIdx.y, n00 = blockIdx.x*4;
  if (tid < NP) { float s,c; sincosf(TWO_PI*(float)tid/(float)NP,&s,&c); tab[tid]=make_float2(c,s); }
  const float* xim = x + (size_t)img*NX*NX;
  for (int e = tid; e < 4*NP; e += 256) {
    int r = e/NP, n1 = e - r*NP;
    int xr = (n00 + r + 126) & 127, xc = (n1 + 126) & 127;
    ly[e] = xim[xr*NX + xc];
  }
  __syncthreads();
  for (int e = tid; e < 4*NV; e += 256) {
    int r = e/NV, v = e - r*NV;
    const float* lyr = ly + r*NP;
    float ar=0.f, ai=0.f; int kk=0;
    for (int n1=0;n1<NP;n1++){
      float yv = lyr[n1]; float2 t = tab[kk];
      ar += t.x*yv; ai -= t.y*yv;
      kk += v; if (kk>=NP) kk-=NP;
    }
    A[((size_t)img*NP + n00+r)*NV + v] = make_float2(ar, ai);
  }
}

// S2 col-DFT + H: T[v][u] = H[c][v][u] * sum_n0 A[n0][v] W^(u n0). 4-wide v-strip/block.
__global__ __launch_bounds__(256) void k_s2(
    const float2* __restrict__ A, const float2* __restrict__ H,
    float2* __restrict__ T) {
  __shared__ float2 tab[NP];
  __shared__ float2 la[NP*4];   // [n0][j]
  int tid = threadIdx.x, img = blockIdx.y, v0 = blockIdx.x*4, c = img & 63;
  if (tid < NP){ float s,cc; sincosf(TWO_PI*(float)tid/(float)NP,&s,&cc); tab[tid]=make_float2(cc,s); }
  for (int e = tid; e < NP*4; e += 256) {
    int n0 = e>>2, j = e&3, v = v0+j;
    la[e] = (v < NV) ? A[((size_t)img*NP + n0)*NV + v] : make_float2(0.f,0.f);
  }
  __syncthreads();
  for (int e = tid; e < 4*NP; e += 256) {
    int j = e/NP, u = e - j*NP, v = v0 + j;
    float ar=0.f, ai=0.f; int kk=0;
    for (int n0=0; n0<NP; n0++) {
      float2 a = la[n0*4 + j]; float2 t = tab[kk];   // W^(u n0) = (t.x, -t.y)
      ar += a.x*t.x + a.y*t.y;
      ai += a.y*t.x - a.x*t.y;
      kk += u; if (kk>=NP) kk-=NP;
    }
    if (v < NV) {
      float2 h = H[((size_t)c*NV + v)*NP + u];
      T[((size_t)img*NV + v)*NP + u] = make_float2(ar*h.x - ai*h.y, ar*h.y + ai*h.x);
    }
  }
}

// S3 col-inverse: U[v][n0] = sum_u conj(W)^(n0 u) T[v][u]. Coalesced row reads of T.
__global__ __launch_bounds__(256) void k_s3(
    const float2* __restrict__ T, float2* __restrict__ U) {
  __shared__ float2 tab[NP];
  __shared__ float2 lt[4*NP];   // [j][u]
  int tid = threadIdx.x, img = blockIdx.y, v0 = blockIdx.x*4;
  if (tid < NP){ float s,c; sincosf(TWO_PI*(float)tid/(float)NP,&s,&c); tab[tid]=make_float2(c,s); }
  for (int e = tid; e < 4*NP; e += 256) {
    int j = e/NP, u = e - j*NP, v = v0+j;
    lt[e] = (v < NV) ? T[((size_t)img*NV + v)*NP + u] : make_float2(0.f,0.f);
  }
  __syncthreads();
  for (int e = tid; e < 4*NP; e += 256) {
    int j = e/NP, n0 = e - j*NP, v = v0 + j;
    const float2* ltr = lt + j*NP;
    float ar=0.f, ai=0.f; int kk=0;
    for (int u=0; u<NP; u++) {
      float2 f = ltr[u]; float2 t = tab[kk];        // conj(W)^(n0 u) = (t.x, +t.y)
      ar += f.x*t.x - f.y*t.y;
      ai += f.x*t.y + f.y*t.x;
      kk += n0; if (kk>=NP) kk-=NP;
    }
    if (v < NV) U[((size_t)img*NV + v)*NP + n0] = make_float2(ar, ai);
  }
}

// S4 row real inverse (half-spectrum): rho[n0][n1] =
//   ( U[0][n0].x + (-1)^n1 U[66][n0].x + 2*sum_{v=1}^{65} Re(U[v][n0] conj(W)^(v n1)) ) / NPP
__global__ __launch_bounds__(256) void k_s4(
    const float2* __restrict__ U, float* __restrict__ rho) {
  __shared__ float2 tab[NP];
  __shared__ float2 lu[NV*4];   // [v][r]
  int tid = threadIdx.x, img = blockIdx.y, n00 = blockIdx.x*4;
  if (tid < NP){ float s,c; sincosf(TWO_PI*(float)tid/(float)NP,&s,&c); tab[tid]=make_float2(c,s); }
  for (int e = tid; e < NV*4; e += 256) {
    int v = e>>2, r = e&3;
    lu[e] = U[((size_t)img*NV + v)*NP + n00 + r];
  }
  __syncthreads();
  for (int e = tid; e < 4*NP; e += 256) {
    int r = e/NP, n1 = e - r*NP;
    float acc = 0.f; int kk = n1;                   // v starts at 1
    for (int v=1; v<NV-1; v++) {
      float2 a = lu[v*4 + r]; float2 t = tab[kk];   // conj(W)^(v n1) = (t.x, +t.y)
      acc += a.x*t.x - a.y*t.y;
      kk += n1; if (kk>=NP) kk-=NP;
    }
    float dc = lu[r].x;
    float ny = lu[66*4 + r].x;
    float res = dc + ((n1 & 1) ? -ny : ny) + 2.f*acc;
    rho[(size_t)img*NPP + (size_t)(n00+r)*NP + n1] = res * (1.0f/(float)NPP);
  }
}

// epilogue: out = gelu( x_up + subpixel 3x3 taps of K over zero-upsampled rho )
__global__ __launch_bounds__(256) void k_epilogue(
    const float* __restrict__ x, const float* __restrict__ wgt,
    const float* __restrict__ rho, float* __restrict__ out) {
  int idx = blockIdx.x * 256 + threadIdx.x;
  int o1 = idx & 255;
  int o0 = (idx >> 8) & 255;
  int img = idx >> 16;
  int c = img & 63;
  int n0 = (o0 + 4) >> 1, n1 = (o1 + 4) >> 1;
  int p0 = o0 & 1, p1 = o1 & 1;
  const float* rim = rho + (size_t)img*NPP;
  int base = n0*NP + n1;
  float r00 = rim[base], r01 = rim[base+1], r10 = rim[base+NP], r11 = rim[base+NP+1];
  const float* w = wgt + c*9;
  float wa = p0 ? (p1 ? w[0] : w[1]) : (p1 ? w[3] : w[4]);
  float wb = p1 ? (p0 ? w[2] : w[5]) : 0.f;
  float wc = p0 ? (p1 ? w[6] : w[7]) : 0.f;
  float wd = (p0 & p1) ? w[8] : 0.f;
  float S = wa*r00 + wb*r01 + wc*r10 + wd*r11;
  float xv = x[(size_t)img*NX*NX + (n0-2)*NX + (n1-2)];
  float z = xv + S;
  out[idx] = 0.5f*z*(1.0f + erff(z*0.70710678118654752f));
}

extern "C" void kernel_launch(void* const* d_in, const int* in_sizes, int n_in,
                              void* d_out, int out_size, void* d_ws, size_t ws_size,
                              hipStream_t stream) {
  const float* x    = (const float*)d_in[0];
  const float* wgt  = (const float*)d_in[1];
  const float* bias = (const float*)d_in[2];
  float* ws = (float*)d_ws;
  float2* H   = (float2*)(ws + OFF_H);
  float2* A   = (float2*)(ws + OFF_A);
  float2* T   = (float2*)(ws + OFF_T);
  float2* U   = (float2*)(ws + OFF_U);
  float*  rho = ws + OFF_RHO;
  float* out = (float*)d_out;

  k_compute_H<<<dim3((NV*NP + 255)/256, NCH), 256, 0, stream>>>(wgt, bias, H);
  k_s1 <<<dim3(33, NIMG), 256, 0, stream>>>(x, A);
  k_s2 <<<dim3(17, NIMG), 256, 0, stream>>>(A, H, T);
  k_s3 <<<dim3(17, NIMG), 256, 0, stream>>>(T, U);
  k_s4 <<<dim3(33, NIMG), 256, 0, stream>>>(U, rho);
  k_epilogue<<<(NIMG*NO*NO)/256, 256, 0, stream>>>(x, wgt, rho, out);
}